// Round 1
// baseline (1938.214 us; speedup 1.0000x reference)
//
#include <hip/hip_runtime.h>

// CapsuleLayer dynamic routing, MI355X.
// B=64 batch, I=2048 input caps, L=16 in_dim, J=64 out caps, K=32 out dim.
// Strategy: never materialize u_hat (1 GiB). Each routing iteration is one
// streaming pass recomputing u_hat via f16 MFMA (16x16x16, K = L = 16).
// Logits are linear in u_hat: b_r = (sum of previous v)·u_hat, so no logit storage.

#define B_ 64
#define I_ 2048
#define L_ 16
#define J_ 64
#define K_ 32
#define N_ 2048  // J_*K_

typedef _Float16 half4_t __attribute__((ext_vector_type(4)));
typedef _Float16 half8_t __attribute__((ext_vector_type(8)));
typedef float f32x4 __attribute__((ext_vector_type(4)));

// ---- cast W: [j][i][k][l] fp32 -> [i][n=j*32+k][l] f16 (64 KB contiguous slice per i)
__global__ __launch_bounds__(256) void cast_w_kernel(const float* __restrict__ W,
                                                     _Float16* __restrict__ Wh) {
    unsigned tid = blockIdx.x * 256u + threadIdx.x;  // (j,i,k), k fastest
    unsigned k = tid & 31u;
    unsigned i = (tid >> 5) & (I_ - 1u);
    unsigned j = tid >> 16;
    const float* src = W + ((size_t)(j * I_ + i) * K_ + k) * L_;
    half8_t h0, h1;
#pragma unroll
    for (int e = 0; e < 8; ++e) h0[e] = (_Float16)src[e];
#pragma unroll
    for (int e = 0; e < 8; ++e) h1[e] = (_Float16)src[8 + e];
    _Float16* dst = Wh + ((size_t)i * N_ + (j * K_ + k)) * L_;
    *(half8_t*)dst = h0;
    *(half8_t*)(dst + 8) = h1;
}

// ---- cast x: [b][i][l] fp32 -> [i][b][l] f16
__global__ __launch_bounds__(256) void cast_x_kernel(const float* __restrict__ X,
                                                     _Float16* __restrict__ Xh) {
    unsigned tid = blockIdx.x * 256u + threadIdx.x;  // (i,b), b fastest
    unsigned b = tid & 63u;
    unsigned i = tid >> 6;
    const float* src = X + (size_t)(b * I_ + i) * L_;
    half8_t h0, h1;
#pragma unroll
    for (int e = 0; e < 8; ++e) h0[e] = (_Float16)src[e];
#pragma unroll
    for (int e = 0; e < 8; ++e) h1[e] = (_Float16)src[8 + e];
    _Float16* dst = Xh + (size_t)(i * B_ + b) * L_;
    *(half8_t*)dst = h0;
    *(half8_t*)(dst + 8) = h1;
}

// ---- routing pass.
// Grid = CH*4 blocks: chunk = blk>>2 (i-range), bg = blk&3 (16 batches).
// Block = 4 waves; wave w owns j in [16w,16w+16) i.e. n in [512w, 512w+512).
// MODE 0: c = 1 (uniform; 1/64 folded into reduce). MODE 1: c = softmax_j(wv·u_hat).
// MFMA 16x16x16 f16: A = x[b(16) x l(16)], B = W[l(16) x n(16)], D per lane:
//   row b = (lane>>4)*4 + r, col n = lane&15.
template <int MODE>
__global__ __launch_bounds__(256) void pass_kernel(const _Float16* __restrict__ Wh,
                                                   const _Float16* __restrict__ Xh,
                                                   const float* __restrict__ wvec,
                                                   float* __restrict__ partials,
                                                   int CH, int ICH) {
    __shared__ _Float16 wvl[16 * N_];  // 64 KB: (b_local, j, k) accumulated-v in f16
    __shared__ float zbuf[16 * J_];    // 4 KB: logits -> softmax probs per (b_local, j)

    const int tid = threadIdx.x;
    const int w = tid >> 6;    // wave = j-quarter
    const int l = tid & 63;    // lane
    const int g = l >> 4;      // row group (4 b's per group)
    const int ln = l & 15;     // within-group lane = n-col / k-offset
    const int blk = blockIdx.x;
    const int chunk = blk >> 2;
    const int bg = blk & 3;

    if (MODE) {
        const float* src = wvec + (size_t)bg * 16 * N_;
#pragma unroll 4
        for (int m = 0; m < 128; ++m) {
            int idx = m * 256 + tid;
            wvl[idx] = (_Float16)src[idx];
        }
        __syncthreads();
    }

    float s_acc[32][4];
#pragma unroll
    for (int a = 0; a < 32; ++a)
#pragma unroll
        for (int r = 0; r < 4; ++r) s_acc[a][r] = 0.f;

    const int i0 = chunk * ICH;
    for (int ii = 0; ii < ICH; ++ii) {
        const int i = i0 + ii;
        // A fragment: x[b = bg*16 + (l&15)][ldim = g*4 .. g*4+3]
        const _Float16* xp = Xh + (size_t)i * (B_ * L_) + (bg * 16 + ln) * L_ + g * 4;
        half4_t afrag = *(const half4_t*)xp;
        const _Float16* wbase = Wh + (size_t)i * ((size_t)N_ * L_);
        f32x4 z4 = {0.f, 0.f, 0.f, 0.f};

        if (MODE) {
            // sweep 1: logits z[b][j] = wv[b,j,:]·u_hat[b,j,i,:]
#pragma unroll
            for (int j0 = 0; j0 < 16; ++j0) {
                const int j = w * 16 + j0;
                float p0 = 0.f, p1 = 0.f, p2 = 0.f, p3 = 0.f;
#pragma unroll
                for (int h = 0; h < 2; ++h) {
                    const int n = w * 512 + j0 * 32 + h * 16 + ln;
                    half4_t bfrag = *(const half4_t*)(wbase + (size_t)n * L_ + g * 4);
                    f32x4 u = __builtin_amdgcn_mfma_f32_16x16x16f16(afrag, bfrag, z4, 0, 0, 0);
                    const int kk = h * 16 + ln;
                    const int jb = j * K_ + kk;
                    p0 += u[0] * (float)wvl[(4 * g + 0) * N_ + jb];
                    p1 += u[1] * (float)wvl[(4 * g + 1) * N_ + jb];
                    p2 += u[2] * (float)wvl[(4 * g + 2) * N_ + jb];
                    p3 += u[3] * (float)wvl[(4 * g + 3) * N_ + jb];
                }
                // reduce over the 16 lanes of the row-group (k dimension)
#pragma unroll
                for (int m = 1; m < 16; m <<= 1) {
                    p0 += __shfl_xor(p0, m, 64);
                    p1 += __shfl_xor(p1, m, 64);
                    p2 += __shfl_xor(p2, m, 64);
                    p3 += __shfl_xor(p3, m, 64);
                }
                if (ln < 4) {
                    float val = (ln == 0) ? p0 : ((ln == 1) ? p1 : ((ln == 2) ? p2 : p3));
                    zbuf[(4 * g + ln) * J_ + j] = val;
                }
            }
            __syncthreads();
            // softmax over j (axis=1) per (b,i): wave w handles b rows 4w..4w+3, lane = j
#pragma unroll
            for (int bb = 0; bb < 4; ++bb) {
                const int brow = 4 * w + bb;
                float zv = zbuf[brow * J_ + l];
                float mx = zv;
#pragma unroll
                for (int m = 32; m >= 1; m >>= 1) mx = fmaxf(mx, __shfl_xor(mx, m, 64));
                float ev = __expf(zv - mx);
                float dn = ev;
#pragma unroll
                for (int m = 32; m >= 1; m >>= 1) dn += __shfl_xor(dn, m, 64);
                zbuf[brow * J_ + l] = ev / dn;
            }
            __syncthreads();
        }

        // sweep 2: s_acc += c * u_hat
#pragma unroll
        for (int j0 = 0; j0 < 16; ++j0) {
            const int j = w * 16 + j0;
            float c0 = 1.f, c1 = 1.f, c2 = 1.f, c3 = 1.f;
            if (MODE) {
                c0 = zbuf[(4 * g + 0) * J_ + j];
                c1 = zbuf[(4 * g + 1) * J_ + j];
                c2 = zbuf[(4 * g + 2) * J_ + j];
                c3 = zbuf[(4 * g + 3) * J_ + j];
            }
#pragma unroll
            for (int h = 0; h < 2; ++h) {
                const int n = w * 512 + j0 * 32 + h * 16 + ln;
                half4_t bfrag = *(const half4_t*)(wbase + (size_t)n * L_ + g * 4);
                f32x4 u = __builtin_amdgcn_mfma_f32_16x16x16f16(afrag, bfrag, z4, 0, 0, 0);
                const int nt = 2 * j0 + h;
                s_acc[nt][0] += c0 * u[0];
                s_acc[nt][1] += c1 * u[1];
                s_acc[nt][2] += c2 * u[2];
                s_acc[nt][3] += c3 * u[3];
            }
        }
        if (MODE) __syncthreads();  // zbuf reused next i
    }

    // flush partial s for this (b-group, chunk)
#pragma unroll
    for (int j0 = 0; j0 < 16; ++j0)
#pragma unroll
        for (int h = 0; h < 2; ++h) {
            const int nt = 2 * j0 + h;
            const int n = w * 512 + j0 * 32 + h * 16 + ln;
#pragma unroll
            for (int r = 0; r < 4; ++r) {
                const int b = bg * 16 + 4 * g + r;
                partials[((size_t)b * CH + chunk) * N_ + n] = s_acc[nt][r];
            }
        }
}

// ---- reduce partials over chunks + squash; update running v-sum / write output.
// grid = 64 b * 8 slices; thread owns one n. STEP0: s *= 1/64, wv = v.
// STEP1: wv += v. STEP2: out = v.
__global__ __launch_bounds__(256) void reduce_kernel(const float* __restrict__ partials,
                                                     float* __restrict__ wvec,
                                                     float* __restrict__ out,
                                                     int CH, int STEP) {
    const int b = blockIdx.x >> 3;
    const int s = blockIdx.x & 7;
    const int t = threadIdx.x;
    const int n = s * 256 + t;
    float acc = 0.f;
    for (int ch = 0; ch < CH; ++ch) acc += partials[((size_t)b * CH + ch) * N_ + n];
    if (STEP == 0) acc *= (1.0f / 64.0f);
    // squash over k = n&31 (32-lane contiguous groups)
    float sq = acc * acc;
#pragma unroll
    for (int m = 1; m < 32; m <<= 1) sq += __shfl_xor(sq, m, 64);
    float scale = sq / (1.0f + sq) / sqrtf(sq + 1e-7f);
    float v = acc * scale;
    const size_t idx = (size_t)b * N_ + n;
    if (STEP == 0) wvec[idx] = v;
    else if (STEP == 1) wvec[idx] += v;
    else out[idx] = v;
}

extern "C" void kernel_launch(void* const* d_in, const int* in_sizes, int n_in,
                              void* d_out, int out_size, void* d_ws, size_t ws_size,
                              hipStream_t stream) {
    const float* X = (const float*)d_in[0];   // [64][2048][16]
    const float* W = (const float*)d_in[1];   // [64][2048][32][16]
    float* out = (float*)d_out;               // [64][64][32]
    char* ws = (char*)d_ws;

    const size_t WH_BYTES = (size_t)I_ * N_ * L_ * 2;      // 134217728
    const size_t XH_BYTES = (size_t)I_ * B_ * L_ * 2;      // 4194304
    const size_t WV_BYTES = (size_t)B_ * N_ * 4;           // 524288
    _Float16* Wh = (_Float16*)ws;
    _Float16* Xh = (_Float16*)(ws + WH_BYTES);
    float* wvec = (float*)(ws + WH_BYTES + XH_BYTES);
    float* parts = (float*)(ws + WH_BYTES + XH_BYTES + WV_BYTES);

    const size_t base = WH_BYTES + XH_BYTES + WV_BYTES;
    int CH = 8;
    if (ws_size >= base + 128ull * WV_BYTES) CH = 128;
    else if (ws_size >= base + 64ull * WV_BYTES) CH = 64;
    else if (ws_size >= base + 32ull * WV_BYTES) CH = 32;
    else if (ws_size >= base + 16ull * WV_BYTES) CH = 16;
    const int ICH = I_ / CH;

    cast_w_kernel<<<dim3((J_ * I_ * K_) / 256), dim3(256), 0, stream>>>(W, Wh);
    cast_x_kernel<<<dim3((B_ * I_) / 256), dim3(256), 0, stream>>>(X, Xh);

    // r = 0: c uniform -> s0 = (1/64) * sum_i u_hat ; v0 ; wv = v0
    pass_kernel<0><<<dim3(CH * 4), dim3(256), 0, stream>>>(Wh, Xh, wvec, parts, CH, ICH);
    reduce_kernel<<<dim3(B_ * 8), dim3(256), 0, stream>>>(parts, wvec, out, CH, 0);
    // r = 1: logits = v0·u_hat
    pass_kernel<1><<<dim3(CH * 4), dim3(256), 0, stream>>>(Wh, Xh, wvec, parts, CH, ICH);
    reduce_kernel<<<dim3(B_ * 8), dim3(256), 0, stream>>>(parts, wvec, out, CH, 1);
    // r = 2: logits = (v0+v1)·u_hat
    pass_kernel<1><<<dim3(CH * 4), dim3(256), 0, stream>>>(Wh, Xh, wvec, parts, CH, ICH);
    reduce_kernel<<<dim3(B_ * 8), dim3(256), 0, stream>>>(parts, wvec, out, CH, 2);

    (void)in_sizes; (void)n_in; (void)out_size;
}

// Round 3
// 759.715 us; speedup vs baseline: 2.5512x; 2.5512x over previous
//
#include <hip/hip_runtime.h>

// CapsuleLayer dynamic routing, MI355X (gfx950).
// B=64, I=2048 (input caps), L=16 (in_dim), J=64 (out caps), K=32 (out dim).
// u_hat is never materialized (1 GiB). Routing logits are linear in u_hat:
// b_r = (sum of previous v) . u_hat, so each routing iteration is:
//   ZSM kernel: z[b,j,i] = wv.u_hat via MFMA, softmax over j -> c (f16, global)
//   S kernel:   s[b,j,k] = sum_i c * u_hat via MFMA -> f16 partials per i-chunk
//   reduce:     sum partials, squash, update wv fragments (f16, MFMA-reg layout)
// MFMA 32x32x16 f16, D = [k-rows 32 x b-cols 32]: one j's full k-dim lives in a
// lane's 16 acc regs -> logit contraction is 16 in-lane FMAs + 1 shfl_xor(32).
// R2 bug fixed here: each lane's acc covers TWO batches (kb and kb+32); wvz is
// now [j][h2][b:64][r:16] and zsm preloads BOTH per-batch wv fragment sets.

#define B_ 64
#define I_ 2048
#define L_ 16
#define J_ 64
#define K_ 32
#define N_ 2048  // J_*K_

typedef _Float16 half4_t __attribute__((ext_vector_type(4)));
typedef _Float16 half8_t __attribute__((ext_vector_type(8)));
typedef float f32x4 __attribute__((ext_vector_type(4)));
typedef float f32x16 __attribute__((ext_vector_type(16)));
typedef float float4_t __attribute__((ext_vector_type(4)));

__device__ __forceinline__ f32x16 fzero16() {
    f32x16 z;
#pragma unroll
    for (int r = 0; r < 16; ++r) z[r] = 0.f;
    return z;
}

// ---- cast W: [j][i][k][l] fp32 -> Wh[i][j][k][l] f16 (1 KB tile per (i,j))
__global__ __launch_bounds__(256) void cast_w_kernel(const float* __restrict__ W,
                                                     _Float16* __restrict__ Wh) {
    unsigned tid = blockIdx.x * 256u + threadIdx.x;  // (j,i,k), k fastest
    unsigned k = tid & 31u;
    unsigned i = (tid >> 5) & (I_ - 1u);
    unsigned j = tid >> 16;
    const float4_t* src = (const float4_t*)(W + ((size_t)(j * I_ + i) * K_ + k) * L_);
    float4_t f0 = src[0], f1 = src[1], f2 = src[2], f3 = src[3];
    half8_t h0, h1;
#pragma unroll
    for (int e = 0; e < 4; ++e) {
        h0[e] = (_Float16)f0[e];
        h0[4 + e] = (_Float16)f1[e];
        h1[e] = (_Float16)f2[e];
        h1[4 + e] = (_Float16)f3[e];
    }
    _Float16* dst = Wh + ((size_t)(i * J_ + j) * K_ + k) * L_;
    *(half8_t*)dst = h0;
    *(half8_t*)(dst + 8) = h1;
}

// ---- cast x: [b][i][l] fp32 -> Xh[i][b][l] f16
__global__ __launch_bounds__(256) void cast_x_kernel(const float* __restrict__ X,
                                                     _Float16* __restrict__ Xh) {
    unsigned tid = blockIdx.x * 256u + threadIdx.x;  // (i,b), b fastest
    unsigned b = tid & 63u;
    unsigned i = tid >> 6;
    const float4_t* src = (const float4_t*)(X + (size_t)(b * I_ + i) * L_);
    float4_t f0 = src[0], f1 = src[1], f2 = src[2], f3 = src[3];
    half8_t h0, h1;
#pragma unroll
    for (int e = 0; e < 4; ++e) {
        h0[e] = (_Float16)f0[e];
        h0[4 + e] = (_Float16)f1[e];
        h1[e] = (_Float16)f2[e];
        h1[4 + e] = (_Float16)f3[e];
    }
    _Float16* dst = Xh + (size_t)(i * B_ + b) * L_;
    *(half8_t*)dst = h0;
    *(half8_t*)(dst + 8) = h1;
}

// ---- ZSM: logits + softmax -> c (f16) for one routing iteration.
// Grid: I_/ZICH blocks x 512 threads (8 waves). Wave w owns j in [8w, 8w+8).
// wvz layout: [j][h2][b:64][r:16] f16 where k = (r&3) + 8*(r>>2) + 4*h2.
__global__ __launch_bounds__(512) void zsm_kernel(const _Float16* __restrict__ Wh,
                                                  const _Float16* __restrict__ Xh,
                                                  const _Float16* __restrict__ wvz,
                                                  _Float16* __restrict__ cbuf,
                                                  int ZICH) {
    __shared__ float zb[64 * 65];  // [b][j] logits, pad 65 -> conflict-free
    const int tid = threadIdx.x;
    const int w = tid >> 6;
    const int l = tid & 63;
    const int h2 = l >> 5;
    const int kb = l & 31;  // A row (k) / B,D col (b within group)

    // preload wv fragments for this wave's 8 j, BOTH batch groups of this lane:
    // batch kb (group 0) and batch kb+32 (group 1); 16 f16 per (j, group).
    half8_t wvr[8][2][2];
#pragma unroll
    for (int jj = 0; jj < 8; ++jj) {
        const int j = w * 8 + jj;
        const _Float16* p0 = wvz + ((size_t)(j * 2 + h2) * B_ + kb) * 16;
        const _Float16* p1 = wvz + ((size_t)(j * 2 + h2) * B_ + 32 + kb) * 16;
        wvr[jj][0][0] = *(const half8_t*)p0;
        wvr[jj][0][1] = *(const half8_t*)(p0 + 8);
        wvr[jj][1][0] = *(const half8_t*)p1;
        wvr[jj][1][1] = *(const half8_t*)(p1 + 8);
    }

    const int i0 = blockIdx.x * ZICH;
    for (int ii = 0; ii < ZICH; ++ii) {
        const int i = i0 + ii;
        if (ii) __syncthreads();  // prior softmax reads done before zb overwrite
        const _Float16* xb = Xh + (size_t)i * (B_ * L_);
        half8_t xf0 = *(const half8_t*)(xb + kb * L_ + 8 * h2);          // batches 0-31
        half8_t xf1 = *(const half8_t*)(xb + (32 + kb) * L_ + 8 * h2);   // batches 32-63
        const _Float16* wbase = Wh + (size_t)i * (J_ * K_ * L_);
#pragma unroll
        for (int jj = 0; jj < 8; ++jj) {
            const int j = w * 8 + jj;
            half8_t af = *(const half8_t*)(wbase + (size_t)(j * K_ + kb) * L_ + 8 * h2);
            f32x16 acc0 = __builtin_amdgcn_mfma_f32_32x32x16_f16(af, xf0, fzero16(), 0, 0, 0);
            f32x16 acc1 = __builtin_amdgcn_mfma_f32_32x32x16_f16(af, xf1, fzero16(), 0, 0, 0);
            float z0 = 0.f, z1 = 0.f;
#pragma unroll
            for (int r = 0; r < 16; ++r) {
                z0 += acc0[r] * (float)wvr[jj][0][r >> 3][r & 7];
                z1 += acc1[r] * (float)wvr[jj][1][r >> 3][r & 7];
            }
            z0 += __shfl_xor(z0, 32, 64);  // combine disjoint k-halves
            z1 += __shfl_xor(z1, 32, 64);
            if (l < 32) {
                zb[kb * 65 + j] = z0;
                zb[(32 + kb) * 65 + j] = z1;
            }
        }
        __syncthreads();
        // softmax over j=64 per b: thread (b = tid>>3, jo = tid&7) handles j = jo*8+q
        const int b = tid >> 3;
        const int jo = tid & 7;
        float zv[8];
#pragma unroll
        for (int q = 0; q < 8; ++q) zv[q] = zb[b * 65 + jo * 8 + q];
        float mx = zv[0];
#pragma unroll
        for (int q = 1; q < 8; ++q) mx = fmaxf(mx, zv[q]);
        mx = fmaxf(mx, __shfl_xor(mx, 1, 64));
        mx = fmaxf(mx, __shfl_xor(mx, 2, 64));
        mx = fmaxf(mx, __shfl_xor(mx, 4, 64));
        float sm = 0.f;
#pragma unroll
        for (int q = 0; q < 8; ++q) { zv[q] = __expf(zv[q] - mx); sm += zv[q]; }
        sm += __shfl_xor(sm, 1, 64);
        sm += __shfl_xor(sm, 2, 64);
        sm += __shfl_xor(sm, 4, 64);
        const float inv = 1.0f / sm;
#pragma unroll
        for (int q = 0; q < 8; ++q) {
            const int j = jo * 8 + q;
            cbuf[((size_t)j * I_ + i) * B_ + b] = (_Float16)(zv[q] * inv);
        }
    }
}

// ---- S: s[b,j,k] partial sums over an i-chunk, weighted by c (or uniform).
// Grid: SCH*8 blocks x 512 threads; block (chunk = blk>>3, jq = blk&7);
// wave w owns j = jq*8 + w. No LDS; c is a 64B broadcast read per (i,j).
template <int UNIFORM>
__global__ __launch_bounds__(512) void s_kernel(const _Float16* __restrict__ Wh,
                                                const _Float16* __restrict__ Xh,
                                                const _Float16* __restrict__ cbuf,
                                                _Float16* __restrict__ parts,
                                                int SCH, int ICH) {
    const int tid = threadIdx.x;
    const int w = tid >> 6;
    const int l = tid & 63;
    const int h2 = l >> 5;
    const int kb = l & 31;
    const int chunk = blockIdx.x >> 3;
    const int jq = blockIdx.x & 7;
    const int j = jq * 8 + w;

    float s0[16], s1[16];
#pragma unroll
    for (int r = 0; r < 16; ++r) { s0[r] = 0.f; s1[r] = 0.f; }

    const int i0 = chunk * ICH;
    for (int ii = 0; ii < ICH; ++ii) {
        const int i = i0 + ii;
        const _Float16* xb = Xh + (size_t)i * (B_ * L_);
        half8_t xf0 = *(const half8_t*)(xb + kb * L_ + 8 * h2);
        half8_t xf1 = *(const half8_t*)(xb + (32 + kb) * L_ + 8 * h2);
        half8_t af = *(const half8_t*)(Wh + ((size_t)(i * J_ + j) * K_ + kb) * L_ + 8 * h2);
        f32x16 acc0 = __builtin_amdgcn_mfma_f32_32x32x16_f16(af, xf0, fzero16(), 0, 0, 0);
        f32x16 acc1 = __builtin_amdgcn_mfma_f32_32x32x16_f16(af, xf1, fzero16(), 0, 0, 0);
        float c0 = 1.f, c1 = 1.f;
        if (!UNIFORM) {
            const _Float16* cp = cbuf + ((size_t)j * I_ + i) * B_;
            c0 = (float)cp[kb];
            c1 = (float)cp[32 + kb];
        }
#pragma unroll
        for (int r = 0; r < 16; ++r) {
            s0[r] += c0 * acc0[r];
            s1[r] += c1 * acc1[r];
        }
    }
    // flush: parts[b][chunk][n], n = j*32+k ; all 64 lanes write distinct k
#pragma unroll
    for (int r = 0; r < 16; ++r) {
        const int k = (r & 3) + 8 * (r >> 2) + 4 * h2;
        const size_t n = (size_t)j * K_ + k;
        parts[((size_t)kb * SCH + chunk) * N_ + n] = (_Float16)s0[r];
        parts[((size_t)(32 + kb) * SCH + chunk) * N_ + n] = (_Float16)s1[r];
    }
}

// ---- reduce partials + squash; maintain wv fragments (f16, MFMA-reg layout).
// STEP0: s *= 1/64 (uniform softmax), wvz = v. STEP1: wvz += v. STEP2: out = v.
__global__ __launch_bounds__(256) void reduce_kernel(const _Float16* __restrict__ parts,
                                                     _Float16* __restrict__ wvz,
                                                     float* __restrict__ out,
                                                     int SCH, int STEP) {
    const int b = blockIdx.x >> 3;
    const int s = blockIdx.x & 7;
    const int t = threadIdx.x;
    const int n = s * 256 + t;
    const int k = n & 31;
    const int j = n >> 5;
    float acc = 0.f;
    for (int ch = 0; ch < SCH; ++ch) acc += (float)parts[((size_t)b * SCH + ch) * N_ + n];
    if (STEP == 0) acc *= (1.0f / 64.0f);
    // squash over k: 32-lane contiguous groups (k = lane&31)
    float sq = acc * acc;
#pragma unroll
    for (int m = 1; m < 32; m <<= 1) sq += __shfl_xor(sq, m, 64);
    const float scale = sq / (1.0f + sq) / sqrtf(sq + 1e-7f);
    const float v = acc * scale;
    if (STEP == 2) {
        out[(size_t)b * N_ + n] = v;
    } else {
        const int h2 = (k >> 2) & 1;
        const int r = (k & 3) + 4 * (k >> 3);
        const size_t idx = ((size_t)(j * 2 + h2) * B_ + b) * 16 + r;
        const float prev = (STEP == 0) ? 0.f : (float)wvz[idx];
        wvz[idx] = (_Float16)(prev + v);
    }
}

extern "C" void kernel_launch(void* const* d_in, const int* in_sizes, int n_in,
                              void* d_out, int out_size, void* d_ws, size_t ws_size,
                              hipStream_t stream) {
    const float* X = (const float*)d_in[0];  // [64][2048][16]
    const float* W = (const float*)d_in[1];  // [64][2048][32][16]
    float* out = (float*)d_out;              // [64][64][32]
    char* ws = (char*)d_ws;

    const size_t WH_BYTES = (size_t)I_ * J_ * K_ * L_ * 2;   // 134,217,728
    const size_t XH_BYTES = (size_t)I_ * B_ * L_ * 2;        //   4,194,304
    const size_t WVZ_BYTES = (size_t)J_ * 2 * B_ * 16 * 2;   //     262,144
    const size_t CB_BYTES = (size_t)J_ * I_ * B_ * 2;        //  16,777,216
    const size_t FIX = WH_BYTES + XH_BYTES + WVZ_BYTES + CB_BYTES;

    int SCH = 64;  // parts chunks; parts = B*SCH*N f16
    if (ws_size < FIX + (size_t)B_ * 64 * N_ * 2) SCH = 32;
    if (ws_size < FIX + (size_t)B_ * 32 * N_ * 2) SCH = 16;
    const int ICH = I_ / SCH;

    _Float16* Wh = (_Float16*)ws;
    _Float16* Xh = (_Float16*)(ws + WH_BYTES);
    _Float16* wvz = (_Float16*)(ws + WH_BYTES + XH_BYTES);
    _Float16* cbuf = (_Float16*)(ws + WH_BYTES + XH_BYTES + WVZ_BYTES);
    _Float16* parts = (_Float16*)(ws + FIX);

    const int ZICH = 4;  // 512 blocks

    cast_w_kernel<<<dim3((J_ * I_ * K_) / 256), dim3(256), 0, stream>>>(W, Wh);
    cast_x_kernel<<<dim3((B_ * I_) / 256), dim3(256), 0, stream>>>(X, Xh);

    // r = 0: uniform c -> s0 = (1/64) sum_i u_hat; v0; wvz = frag(v0)
    s_kernel<1><<<dim3(SCH * 8), dim3(512), 0, stream>>>(Wh, Xh, nullptr, parts, SCH, ICH);
    reduce_kernel<<<dim3(B_ * 8), dim3(256), 0, stream>>>(parts, wvz, out, SCH, 0);
    // r = 1: logits = v0 . u_hat
    zsm_kernel<<<dim3(I_ / ZICH), dim3(512), 0, stream>>>(Wh, Xh, wvz, cbuf, ZICH);
    s_kernel<0><<<dim3(SCH * 8), dim3(512), 0, stream>>>(Wh, Xh, cbuf, parts, SCH, ICH);
    reduce_kernel<<<dim3(B_ * 8), dim3(256), 0, stream>>>(parts, wvz, out, SCH, 1);
    // r = 2: logits = (v0+v1) . u_hat
    zsm_kernel<<<dim3(I_ / ZICH), dim3(512), 0, stream>>>(Wh, Xh, wvz, cbuf, ZICH);
    s_kernel<0><<<dim3(SCH * 8), dim3(512), 0, stream>>>(Wh, Xh, cbuf, parts, SCH, ICH);
    reduce_kernel<<<dim3(B_ * 8), dim3(256), 0, stream>>>(parts, wvz, out, SCH, 2);

    (void)in_sizes; (void)n_in; (void)out_size;
}

// Round 4
// 328.660 us; speedup vs baseline: 5.8973x; 2.3116x over previous
//
#include <hip/hip_runtime.h>

// CapsuleLayer dynamic routing, MI355X (gfx950).
// B=64, I=2048 (input caps), L=16 (in_dim), J=64 (out caps), K=32 (out dim).
// u_hat never materialized. Logits are linear in u_hat (b_r = (sum of prior v).u_hat):
//   zsm: per (i), ONE WAVE computes all 64 j logits via MFMA; after shfl_xor(32)
//        lane l holds z[batch=l][j] -> wave-private LDS row -> in-lane softmax ->
//        coalesced c[i][j][b] f16 stores. NO barriers, no cross-wave traffic.
//   s:   s[b,j,k] = sum_i c*u_hat via MFMA (wave owns one j, streams i).
//        <CAST=1> variant reads W fp32 directly, converts, writes Wh f16 side-output.
//   reduce: sum chunk partials, squash, maintain wv fragments (f16, MFMA D-layout).
// MFMA 32x32x16 f16: D rows k = (r&3)+8*(r>>2)+4*(lane>>5), cols b = lane&31.

#define B_ 64
#define I_ 2048
#define L_ 16
#define J_ 64
#define K_ 32
#define N_ 2048  // J_*K_

typedef _Float16 half8_t __attribute__((ext_vector_type(8)));
typedef float f32x16 __attribute__((ext_vector_type(16)));
typedef float float4_t __attribute__((ext_vector_type(4)));

__device__ __forceinline__ f32x16 fzero16() {
    f32x16 z;
#pragma unroll
    for (int r = 0; r < 16; ++r) z[r] = 0.f;
    return z;
}

// ---- cast x: [b][i][l] fp32 -> Xh[i][b][l] f16
__global__ __launch_bounds__(256) void cast_x_kernel(const float* __restrict__ X,
                                                     _Float16* __restrict__ Xh) {
    unsigned tid = blockIdx.x * 256u + threadIdx.x;  // (i,b), b fastest
    unsigned b = tid & 63u;
    unsigned i = tid >> 6;
    const float4_t* src = (const float4_t*)(X + (size_t)(b * I_ + i) * L_);
    float4_t f0 = src[0], f1 = src[1], f2 = src[2], f3 = src[3];
    half8_t h0, h1;
#pragma unroll
    for (int e = 0; e < 4; ++e) {
        h0[e] = (_Float16)f0[e];
        h0[4 + e] = (_Float16)f1[e];
        h1[e] = (_Float16)f2[e];
        h1[4 + e] = (_Float16)f3[e];
    }
    _Float16* dst = Xh + (size_t)(i * B_ + b) * L_;
    *(half8_t*)dst = h0;
    *(half8_t*)(dst + 8) = h1;
}

// ---- ZSM: logits + softmax -> c (f16, [i][j][b]) for one routing iteration.
// Grid: 512 blocks x 256 threads (4 waves); wave w handles i = blk*4 + w alone.
// wvz layout: [j][h2][b:64][r:16] f16 where k = (r&3) + 8*(r>>2) + 4*h2.
__global__ __launch_bounds__(256) void zsm_kernel(const _Float16* __restrict__ Wh,
                                                  const _Float16* __restrict__ Xh,
                                                  const _Float16* __restrict__ wvz,
                                                  _Float16* __restrict__ cbuf) {
    __shared__ float zl[4][64][65];  // wave-private rows; pad 65 -> conflict-free
    const int w = threadIdx.x >> 6;
    const int l = threadIdx.x & 63;
    const int h2 = l >> 5;
    const int kb = l & 31;
    const int i = blockIdx.x * 4 + w;

    const _Float16* xb = Xh + (size_t)i * (B_ * L_);
    half8_t xf0 = *(const half8_t*)(xb + kb * L_ + 8 * h2);          // batches 0-31
    half8_t xf1 = *(const half8_t*)(xb + (32 + kb) * L_ + 8 * h2);   // batches 32-63
    const _Float16* wbase = Wh + (size_t)i * (J_ * K_ * L_);

#pragma unroll 4
    for (int j = 0; j < J_; ++j) {
        half8_t af = *(const half8_t*)(wbase + ((size_t)j * K_ + kb) * L_ + 8 * h2);
        const _Float16* wp = wvz + ((size_t)(j * 2 + h2) * B_ + kb) * 16;
        half8_t wv00 = *(const half8_t*)wp;            // batch kb,    regs 0-7
        half8_t wv01 = *(const half8_t*)(wp + 8);      // batch kb,    regs 8-15
        half8_t wv10 = *(const half8_t*)(wp + 512);    // batch kb+32, regs 0-7
        half8_t wv11 = *(const half8_t*)(wp + 520);
        f32x16 acc0 = __builtin_amdgcn_mfma_f32_32x32x16_f16(af, xf0, fzero16(), 0, 0, 0);
        f32x16 acc1 = __builtin_amdgcn_mfma_f32_32x32x16_f16(af, xf1, fzero16(), 0, 0, 0);
        float z0 = 0.f, z1 = 0.f;
#pragma unroll
        for (int r = 0; r < 16; ++r) {
            const float a = (r < 8) ? (float)wv00[r] : (float)wv01[r - 8];
            const float b = (r < 8) ? (float)wv10[r] : (float)wv11[r - 8];
            z0 += acc0[r] * a;
            z1 += acc1[r] * b;
        }
        z0 += __shfl_xor(z0, 32, 64);  // combine disjoint k-halves
        z1 += __shfl_xor(z1, 32, 64);
        // lane l now holds the full logit of batch l in (l<32 ? z0 : z1)
        zl[w][l][j] = (l < 32) ? z0 : z1;
    }

    // in-lane softmax over j for batch b = l (row written exclusively by this lane)
    float zr[64];
#pragma unroll
    for (int q = 0; q < 64; ++q) zr[q] = zl[w][l][q];
    float mx = zr[0];
#pragma unroll
    for (int q = 1; q < 64; ++q) mx = fmaxf(mx, zr[q]);
    float sm = 0.f;
#pragma unroll
    for (int q = 0; q < 64; ++q) {
        zr[q] = __expf(zr[q] - mx);
        sm += zr[q];
    }
    const float inv = 1.0f / sm;
    _Float16* cb = cbuf + (size_t)i * (J_ * B_) + l;
#pragma unroll
    for (int q = 0; q < 64; ++q) cb[(size_t)q * B_] = (_Float16)(zr[q] * inv);  // c[i][q][l]
}

// ---- S: s[b,j,k] partial sums over an i-chunk, weighted by c (or uniform).
// Grid: SCH*8 blocks x 512 threads; block (chunk = blk>>3, jq = blk&7);
// wave w owns j = jq*8 + w. CAST=1: read W fp32, convert, write Wh side-output.
template <int UNIFORM, int CAST>
__global__ __launch_bounds__(512) void s_kernel(const float* __restrict__ Wf,
                                                const _Float16* __restrict__ Wh_in,
                                                _Float16* __restrict__ Wh_out,
                                                const _Float16* __restrict__ Xh,
                                                const _Float16* __restrict__ cbuf,
                                                _Float16* __restrict__ parts,
                                                int SCH, int ICH) {
    const int tid = threadIdx.x;
    const int w = tid >> 6;
    const int l = tid & 63;
    const int h2 = l >> 5;
    const int kb = l & 31;
    const int chunk = blockIdx.x >> 3;
    const int jq = blockIdx.x & 7;
    const int j = jq * 8 + w;

    float s0[16], s1[16];
#pragma unroll
    for (int r = 0; r < 16; ++r) { s0[r] = 0.f; s1[r] = 0.f; }

    const int i0 = chunk * ICH;
    for (int ii = 0; ii < ICH; ++ii) {
        const int i = i0 + ii;
        const _Float16* xb = Xh + (size_t)i * (B_ * L_);
        half8_t xf0 = *(const half8_t*)(xb + kb * L_ + 8 * h2);
        half8_t xf1 = *(const half8_t*)(xb + (32 + kb) * L_ + 8 * h2);
        half8_t af;
        if (CAST) {
            const float4_t* wsrc =
                (const float4_t*)(Wf + ((size_t)(j * I_ + i) * K_ + kb) * L_ + 8 * h2);
            float4_t a0 = wsrc[0], a1 = wsrc[1];
#pragma unroll
            for (int e = 0; e < 4; ++e) {
                af[e] = (_Float16)a0[e];
                af[4 + e] = (_Float16)a1[e];
            }
            *(half8_t*)(Wh_out + ((size_t)(i * J_ + j) * K_ + kb) * L_ + 8 * h2) = af;
        } else {
            af = *(const half8_t*)(Wh_in + ((size_t)(i * J_ + j) * K_ + kb) * L_ + 8 * h2);
        }
        f32x16 acc0 = __builtin_amdgcn_mfma_f32_32x32x16_f16(af, xf0, fzero16(), 0, 0, 0);
        f32x16 acc1 = __builtin_amdgcn_mfma_f32_32x32x16_f16(af, xf1, fzero16(), 0, 0, 0);
        float c0 = 1.f, c1 = 1.f;
        if (!UNIFORM) {
            const _Float16* cp = cbuf + (size_t)i * (J_ * B_) + (size_t)j * B_;
            c0 = (float)cp[kb];
            c1 = (float)cp[32 + kb];
        }
#pragma unroll
        for (int r = 0; r < 16; ++r) {
            s0[r] += c0 * acc0[r];
            s1[r] += c1 * acc1[r];
        }
    }
    // flush: parts[b][chunk][n], n = j*32+k ; all 64 lanes write distinct k
#pragma unroll
    for (int r = 0; r < 16; ++r) {
        const int k = (r & 3) + 8 * (r >> 2) + 4 * h2;
        const size_t n = (size_t)j * K_ + k;
        parts[((size_t)kb * SCH + chunk) * N_ + n] = (_Float16)s0[r];
        parts[((size_t)(32 + kb) * SCH + chunk) * N_ + n] = (_Float16)s1[r];
    }
}

// ---- reduce partials + squash; maintain wv fragments (f16, MFMA D-layout).
// STEP0: s *= 1/64 (uniform softmax), wvz = v. STEP1: wvz += v. STEP2: out = v.
__global__ __launch_bounds__(256) void reduce_kernel(const _Float16* __restrict__ parts,
                                                     _Float16* __restrict__ wvz,
                                                     float* __restrict__ out,
                                                     int SCH, int STEP) {
    const int b = blockIdx.x >> 3;
    const int s = blockIdx.x & 7;
    const int t = threadIdx.x;
    const int n = s * 256 + t;
    const int k = n & 31;
    const int j = n >> 5;
    float acc = 0.f;
    for (int ch = 0; ch < SCH; ++ch) acc += (float)parts[((size_t)b * SCH + ch) * N_ + n];
    if (STEP == 0) acc *= (1.0f / 64.0f);
    // squash over k: 32-lane contiguous groups (k = lane&31)
    float sq = acc * acc;
#pragma unroll
    for (int m = 1; m < 32; m <<= 1) sq += __shfl_xor(sq, m, 64);
    const float scale = sq / (1.0f + sq) / sqrtf(sq + 1e-7f);
    const float v = acc * scale;
    if (STEP == 2) {
        out[(size_t)b * N_ + n] = v;
    } else {
        const int h2 = (k >> 2) & 1;
        const int r = (k & 3) + 4 * (k >> 3);
        const size_t idx = ((size_t)(j * 2 + h2) * B_ + b) * 16 + r;
        const float prev = (STEP == 0) ? 0.f : (float)wvz[idx];
        wvz[idx] = (_Float16)(prev + v);
    }
}

extern "C" void kernel_launch(void* const* d_in, const int* in_sizes, int n_in,
                              void* d_out, int out_size, void* d_ws, size_t ws_size,
                              hipStream_t stream) {
    const float* X = (const float*)d_in[0];  // [64][2048][16]
    const float* W = (const float*)d_in[1];  // [64][2048][32][16]
    float* out = (float*)d_out;              // [64][64][32]
    char* ws = (char*)d_ws;

    const size_t WH_BYTES = (size_t)I_ * J_ * K_ * L_ * 2;   // 134,217,728
    const size_t XH_BYTES = (size_t)I_ * B_ * L_ * 2;        //   4,194,304
    const size_t WVZ_BYTES = (size_t)J_ * 2 * B_ * 16 * 2;   //     262,144
    const size_t CB_BYTES = (size_t)I_ * J_ * B_ * 2;        //  16,777,216
    const size_t FIX = WH_BYTES + XH_BYTES + WVZ_BYTES + CB_BYTES;

    int SCH = 64;  // parts chunks; parts = B*SCH*N f16
    if (ws_size < FIX + (size_t)B_ * 64 * N_ * 2) SCH = 32;
    if (ws_size < FIX + (size_t)B_ * 32 * N_ * 2) SCH = 16;
    const int ICH = I_ / SCH;

    _Float16* Wh = (_Float16*)ws;
    _Float16* Xh = (_Float16*)(ws + WH_BYTES);
    _Float16* wvz = (_Float16*)(ws + WH_BYTES + XH_BYTES);
    _Float16* cbuf = (_Float16*)(ws + WH_BYTES + XH_BYTES + WVZ_BYTES);
    _Float16* parts = (_Float16*)(ws + FIX);

    cast_x_kernel<<<dim3((B_ * I_) / 256), dim3(256), 0, stream>>>(X, Xh);

    // r = 0: uniform c; fused W fp32 read + f16 cast (writes Wh) + s0 accumulate
    s_kernel<1, 1><<<dim3(SCH * 8), dim3(512), 0, stream>>>(W, nullptr, Wh, Xh, nullptr,
                                                            parts, SCH, ICH);
    reduce_kernel<<<dim3(B_ * 8), dim3(256), 0, stream>>>(parts, wvz, out, SCH, 0);
    // r = 1: logits = v0 . u_hat
    zsm_kernel<<<dim3(I_ / 4), dim3(256), 0, stream>>>(Wh, Xh, wvz, cbuf);
    s_kernel<0, 0><<<dim3(SCH * 8), dim3(512), 0, stream>>>(nullptr, Wh, nullptr, Xh, cbuf,
                                                            parts, SCH, ICH);
    reduce_kernel<<<dim3(B_ * 8), dim3(256), 0, stream>>>(parts, wvz, out, SCH, 1);
    // r = 2: logits = (v0+v1) . u_hat
    zsm_kernel<<<dim3(I_ / 4), dim3(256), 0, stream>>>(Wh, Xh, wvz, cbuf);
    s_kernel<0, 0><<<dim3(SCH * 8), dim3(512), 0, stream>>>(nullptr, Wh, nullptr, Xh, cbuf,
                                                            parts, SCH, ICH);
    reduce_kernel<<<dim3(B_ * 8), dim3(256), 0, stream>>>(parts, wvz, out, SCH, 2);

    (void)in_sizes; (void)n_in; (void)out_size;
}

// Round 5
// 290.283 us; speedup vs baseline: 6.6770x; 1.1322x over previous
//
#include <hip/hip_runtime.h>

// CapsuleLayer dynamic routing, MI355X (gfx950).
// B=64, I=2048 (input caps), L=16 (in_dim), J=64 (out caps), K=32 (out dim).
// u_hat never materialized. Logits are linear in u_hat (b_r = (sum of prior v).u_hat).
// All W-streaming passes share one shape: wave owns j, streams i, MFMA 32x32x16 f16
// (D rows k = (r&3)+8*(r>>2)+4*(lane>>5), cols b = lane&31).
// Per routing iteration r>0:
//   zcalc: e[j][i][b] = exp(wv . u_hat)  (f16; |z|<~6 so no max-subtraction needed)
//   dsum:  rD[i][b] = 1/sum_j e
//   s:     s[b,j,k] partials = sum_i (e*rD) * u_hat   -> f16 chunk partials
//   reduce: sum partials, squash, maintain wv fragments (f16, MFMA D-layout)
// r=0 uses uniform c=1/64 (folded into reduce); its s-pass fuses the fp32->f16
// cast of W (reads W fp32 once, writes Wh side-output).

#define B_ 64
#define I_ 2048
#define L_ 16
#define J_ 64
#define K_ 32
#define N_ 2048  // J_*K_

typedef _Float16 half8_t __attribute__((ext_vector_type(8)));
typedef float f32x16 __attribute__((ext_vector_type(16)));
typedef float float4_t __attribute__((ext_vector_type(4)));

__device__ __forceinline__ f32x16 fzero16() {
    f32x16 z;
#pragma unroll
    for (int r = 0; r < 16; ++r) z[r] = 0.f;
    return z;
}

// ---- cast x: [b][i][l] fp32 -> Xh[i][b][l] f16
__global__ __launch_bounds__(256) void cast_x_kernel(const float* __restrict__ X,
                                                     _Float16* __restrict__ Xh) {
    unsigned tid = blockIdx.x * 256u + threadIdx.x;  // (i,b), b fastest
    unsigned b = tid & 63u;
    unsigned i = tid >> 6;
    const float4_t* src = (const float4_t*)(X + (size_t)(b * I_ + i) * L_);
    float4_t f0 = src[0], f1 = src[1], f2 = src[2], f3 = src[3];
    half8_t h0, h1;
#pragma unroll
    for (int e = 0; e < 4; ++e) {
        h0[e] = (_Float16)f0[e];
        h0[4 + e] = (_Float16)f1[e];
        h1[e] = (_Float16)f2[e];
        h1[4 + e] = (_Float16)f3[e];
    }
    _Float16* dst = Xh + (size_t)(i * B_ + b) * L_;
    *(half8_t*)dst = h0;
    *(half8_t*)(dst + 8) = h1;
}

// ---- zcalc: e[j][i][b] = exp(z), z = wv . u_hat. Wave owns j, streams i.
// Grid: SCH*8 blocks x 512 threads; block (chunk = blk>>3, jq = blk&7); j = jq*8+w.
// wvz layout: [j][h2][b:64][r:16] f16 where k = (r&3) + 8*(r>>2) + 4*h2.
__global__ __launch_bounds__(512) void zcalc_kernel(const _Float16* __restrict__ Wh,
                                                    const _Float16* __restrict__ Xh,
                                                    const _Float16* __restrict__ wvz,
                                                    _Float16* __restrict__ ebuf,
                                                    int SCH, int ICH) {
    const int tid = threadIdx.x;
    const int w = tid >> 6;
    const int l = tid & 63;
    const int h2 = l >> 5;
    const int kb = l & 31;
    const int chunk = blockIdx.x >> 3;
    const int jq = blockIdx.x & 7;
    const int j = jq * 8 + w;

    // preload wv fragments for own j, both batch groups of this lane (kb, kb+32)
    const _Float16* wp = wvz + ((size_t)(j * 2 + h2) * B_ + kb) * 16;
    const half8_t wv00 = *(const half8_t*)wp;
    const half8_t wv01 = *(const half8_t*)(wp + 8);
    const half8_t wv10 = *(const half8_t*)(wp + 512);  // batch kb+32
    const half8_t wv11 = *(const half8_t*)(wp + 520);

    const int i0 = chunk * ICH;
#pragma unroll 2
    for (int ii = 0; ii < ICH; ++ii) {
        const int i = i0 + ii;
        const _Float16* xb = Xh + (size_t)i * (B_ * L_);
        half8_t xf0 = *(const half8_t*)(xb + kb * L_ + 8 * h2);
        half8_t xf1 = *(const half8_t*)(xb + (32 + kb) * L_ + 8 * h2);
        half8_t af = *(const half8_t*)(Wh + ((size_t)(i * J_ + j) * K_ + kb) * L_ + 8 * h2);
        f32x16 acc0 = __builtin_amdgcn_mfma_f32_32x32x16_f16(af, xf0, fzero16(), 0, 0, 0);
        f32x16 acc1 = __builtin_amdgcn_mfma_f32_32x32x16_f16(af, xf1, fzero16(), 0, 0, 0);
        float z0 = 0.f, z1 = 0.f;
#pragma unroll
        for (int r = 0; r < 16; ++r) {
            const float a = (r < 8) ? (float)wv00[r] : (float)wv01[r - 8];
            const float b = (r < 8) ? (float)wv10[r] : (float)wv11[r - 8];
            z0 += acc0[r] * a;
            z1 += acc1[r] * b;
        }
        z0 += __shfl_xor(z0, 32, 64);  // combine disjoint k-halves
        z1 += __shfl_xor(z1, 32, 64);
        // lane l holds the full logit of batch l; |z| <~ 6, clamp = NaN insurance
        const float zf = fminf((l < 32) ? z0 : z1, 11.0f);
        ebuf[((size_t)j * I_ + i) * B_ + l] = (_Float16)__expf(zf);
    }
}

// ---- dsum: rD[i][b] = 1 / sum_j e[j][i][b]. One wave per i, lane = b.
__global__ __launch_bounds__(256) void dsum_kernel(const _Float16* __restrict__ ebuf,
                                                   float* __restrict__ rD) {
    const int w = threadIdx.x >> 6;
    const int l = threadIdx.x & 63;
    const int i = blockIdx.x * 4 + w;
    float s = 0.f;
#pragma unroll
    for (int j = 0; j < J_; ++j) s += (float)ebuf[((size_t)j * I_ + i) * B_ + l];
    rD[i * B_ + l] = 1.0f / s;
}

// ---- S: s[b,j,k] partial sums over an i-chunk, weighted by c = e*rD (or uniform).
// Grid: SCH*8 blocks x 512 threads; wave owns j = (blk&7)*8 + w, streams i.
// CAST=1: read W fp32, convert, write Wh side-output (r=0 only).
template <int UNIFORM, int CAST>
__global__ __launch_bounds__(512) void s_kernel(const float* __restrict__ Wf,
                                                const _Float16* __restrict__ Wh_in,
                                                _Float16* __restrict__ Wh_out,
                                                const _Float16* __restrict__ Xh,
                                                const _Float16* __restrict__ ebuf,
                                                const float* __restrict__ rD,
                                                _Float16* __restrict__ parts,
                                                int SCH, int ICH) {
    const int tid = threadIdx.x;
    const int w = tid >> 6;
    const int l = tid & 63;
    const int h2 = l >> 5;
    const int kb = l & 31;
    const int chunk = blockIdx.x >> 3;
    const int jq = blockIdx.x & 7;
    const int j = jq * 8 + w;

    float s0[16], s1[16];
#pragma unroll
    for (int r = 0; r < 16; ++r) { s0[r] = 0.f; s1[r] = 0.f; }

    const int i0 = chunk * ICH;
    for (int ii = 0; ii < ICH; ++ii) {
        const int i = i0 + ii;
        const _Float16* xb = Xh + (size_t)i * (B_ * L_);
        half8_t xf0 = *(const half8_t*)(xb + kb * L_ + 8 * h2);
        half8_t xf1 = *(const half8_t*)(xb + (32 + kb) * L_ + 8 * h2);
        half8_t af;
        if (CAST) {
            const float4_t* wsrc =
                (const float4_t*)(Wf + ((size_t)(j * I_ + i) * K_ + kb) * L_ + 8 * h2);
            float4_t a0 = wsrc[0], a1 = wsrc[1];
#pragma unroll
            for (int e = 0; e < 4; ++e) {
                af[e] = (_Float16)a0[e];
                af[4 + e] = (_Float16)a1[e];
            }
            *(half8_t*)(Wh_out + ((size_t)(i * J_ + j) * K_ + kb) * L_ + 8 * h2) = af;
        } else {
            af = *(const half8_t*)(Wh_in + ((size_t)(i * J_ + j) * K_ + kb) * L_ + 8 * h2);
        }
        f32x16 acc0 = __builtin_amdgcn_mfma_f32_32x32x16_f16(af, xf0, fzero16(), 0, 0, 0);
        f32x16 acc1 = __builtin_amdgcn_mfma_f32_32x32x16_f16(af, xf1, fzero16(), 0, 0, 0);
        float c0 = 1.f, c1 = 1.f;
        if (!UNIFORM) {
            const _Float16* ep = ebuf + ((size_t)j * I_ + i) * B_;
            c0 = (float)ep[kb] * rD[i * B_ + kb];
            c1 = (float)ep[32 + kb] * rD[i * B_ + 32 + kb];
        }
#pragma unroll
        for (int r = 0; r < 16; ++r) {
            s0[r] += c0 * acc0[r];
            s1[r] += c1 * acc1[r];
        }
    }
    // flush: parts[b][chunk][n], n = j*32+k ; all 64 lanes write distinct k
#pragma unroll
    for (int r = 0; r < 16; ++r) {
        const int k = (r & 3) + 8 * (r >> 2) + 4 * h2;
        const size_t n = (size_t)j * K_ + k;
        parts[((size_t)kb * SCH + chunk) * N_ + n] = (_Float16)s0[r];
        parts[((size_t)(32 + kb) * SCH + chunk) * N_ + n] = (_Float16)s1[r];
    }
}

// ---- reduce partials + squash; maintain wv fragments (f16, MFMA D-layout).
// STEP0: s *= 1/64 (uniform softmax), wvz = v. STEP1: wvz += v. STEP2: out = v.
__global__ __launch_bounds__(256) void reduce_kernel(const _Float16* __restrict__ parts,
                                                     _Float16* __restrict__ wvz,
                                                     float* __restrict__ out,
                                                     int SCH, int STEP) {
    const int b = blockIdx.x >> 3;
    const int s = blockIdx.x & 7;
    const int t = threadIdx.x;
    const int n = s * 256 + t;
    const int k = n & 31;
    const int j = n >> 5;
    float acc = 0.f;
    for (int ch = 0; ch < SCH; ++ch) acc += (float)parts[((size_t)b * SCH + ch) * N_ + n];
    if (STEP == 0) acc *= (1.0f / 64.0f);
    // squash over k: 32-lane contiguous groups (k = lane&31)
    float sq = acc * acc;
#pragma unroll
    for (int m = 1; m < 32; m <<= 1) sq += __shfl_xor(sq, m, 64);
    const float scale = sq / (1.0f + sq) / sqrtf(sq + 1e-7f);
    const float v = acc * scale;
    if (STEP == 2) {
        out[(size_t)b * N_ + n] = v;
    } else {
        const int h2 = (k >> 2) & 1;
        const int r = (k & 3) + 4 * (k >> 3);
        const size_t idx = ((size_t)(j * 2 + h2) * B_ + b) * 16 + r;
        const float prev = (STEP == 0) ? 0.f : (float)wvz[idx];
        wvz[idx] = (_Float16)(prev + v);
    }
}

extern "C" void kernel_launch(void* const* d_in, const int* in_sizes, int n_in,
                              void* d_out, int out_size, void* d_ws, size_t ws_size,
                              hipStream_t stream) {
    const float* X = (const float*)d_in[0];  // [64][2048][16]
    const float* W = (const float*)d_in[1];  // [64][2048][32][16]
    float* out = (float*)d_out;              // [64][64][32]
    char* ws = (char*)d_ws;

    const size_t WH_BYTES = (size_t)I_ * J_ * K_ * L_ * 2;   // 134,217,728
    const size_t XH_BYTES = (size_t)I_ * B_ * L_ * 2;        //   4,194,304
    const size_t WVZ_BYTES = (size_t)J_ * 2 * B_ * 16 * 2;   //     262,144
    const size_t EB_BYTES = (size_t)J_ * I_ * B_ * 2;        //  16,777,216
    const size_t RD_BYTES = (size_t)I_ * B_ * 4;             //     524,288
    const size_t FIX = WH_BYTES + XH_BYTES + WVZ_BYTES + EB_BYTES + RD_BYTES;

    int SCH = 64;  // parts chunks; parts = B*SCH*N f16
    if (ws_size < FIX + (size_t)B_ * 64 * N_ * 2) SCH = 32;
    if (ws_size < FIX + (size_t)B_ * 32 * N_ * 2) SCH = 16;
    const int ICH = I_ / SCH;

    _Float16* Wh = (_Float16*)ws;
    _Float16* Xh = (_Float16*)(ws + WH_BYTES);
    _Float16* wvz = (_Float16*)(ws + WH_BYTES + XH_BYTES);
    _Float16* ebuf = (_Float16*)(ws + WH_BYTES + XH_BYTES + WVZ_BYTES);
    float* rD = (float*)(ws + WH_BYTES + XH_BYTES + WVZ_BYTES + EB_BYTES);
    _Float16* parts = (_Float16*)(ws + FIX);

    cast_x_kernel<<<dim3((B_ * I_) / 256), dim3(256), 0, stream>>>(X, Xh);

    // r = 0: uniform c; fused W fp32 read + f16 cast (writes Wh) + s0 accumulate
    s_kernel<1, 1><<<dim3(SCH * 8), dim3(512), 0, stream>>>(W, nullptr, Wh, Xh, nullptr,
                                                            nullptr, parts, SCH, ICH);
    reduce_kernel<<<dim3(B_ * 8), dim3(256), 0, stream>>>(parts, wvz, out, SCH, 0);

    // r = 1: e = exp(v0 . u_hat); rD; s1
    zcalc_kernel<<<dim3(SCH * 8), dim3(512), 0, stream>>>(Wh, Xh, wvz, ebuf, SCH, ICH);
    dsum_kernel<<<dim3(I_ / 4), dim3(256), 0, stream>>>(ebuf, rD);
    s_kernel<0, 0><<<dim3(SCH * 8), dim3(512), 0, stream>>>(nullptr, Wh, nullptr, Xh, ebuf,
                                                            rD, parts, SCH, ICH);
    reduce_kernel<<<dim3(B_ * 8), dim3(256), 0, stream>>>(parts, wvz, out, SCH, 1);

    // r = 2: e = exp((v0+v1) . u_hat); rD; s2
    zcalc_kernel<<<dim3(SCH * 8), dim3(512), 0, stream>>>(Wh, Xh, wvz, ebuf, SCH, ICH);
    dsum_kernel<<<dim3(I_ / 4), dim3(256), 0, stream>>>(ebuf, rD);
    s_kernel<0, 0><<<dim3(SCH * 8), dim3(512), 0, stream>>>(nullptr, Wh, nullptr, Xh, ebuf,
                                                            rD, parts, SCH, ICH);
    reduce_kernel<<<dim3(B_ * 8), dim3(256), 0, stream>>>(parts, wvz, out, SCH, 2);

    (void)in_sizes; (void)n_in; (void)out_size;
}